// Round 12
// baseline (216.030 us; speedup 1.0000x reference)
//
#include <hip/hip_runtime.h>
#include <hip/hip_fp16.h>
#include <math.h>

#define HID 64
#define HEADS 4
#define GR 64
#define NEG 0.2f
#define NBKT_MAX 512
#define BK_SH 8     // 256 nodes per bucket
#define PART_T 2048 // edges per partition tile
// tmp edge pack: (dst & 255) << 17 | src   -- requires N < 2^17 (N=100000 ok)

typedef _Float16 f16x8 __attribute__((ext_vector_type(8)));
typedef float    f32x4 __attribute__((ext_vector_type(4)));

__device__ __forceinline__ float lrelu(float v){ return v > 0.f ? v : NEG * v; }
__device__ __forceinline__ float elu_(float v){ return v > 0.f ? v : __expf(v) - 1.f; }

// zero pooled sums/counts/bucket-counts; block 0 wave 0 also computes the
// attention-projection constants cvec = [cs0(4), cs1(4), cd0(4), cd1(4)].
// (must run EVERY call: harness does not re-poison ws between timed replays)
__global__ void k_init(float* sums, int* counts, int* bcnt,
                       const float* __restrict__ W1, const float* __restrict__ as1,
                       const float* __restrict__ ad1, float* cvec){
    int i = blockIdx.x * blockDim.x + threadIdx.x;
    if (i < GR * HID) sums[i] = 0.f;
    if (i < GR) counts[i] = 0;
    if (i < NBKT_MAX) bcnt[i] = 0;
    if (blockIdx.x == 0 && threadIdx.x < 64){
        int lane = threadIdx.x;
#pragma unroll
        for (int h = 0; h < HEADS; h++){
            int j = h * HID + lane;
            float s0 = W1[j]       * as1[j];
            float s1 = W1[256 + j] * as1[j];
            float d0 = W1[j]       * ad1[j];
            float d1 = W1[256 + j] * ad1[j];
#pragma unroll
            for (int off = 32; off; off >>= 1){
                s0 += __shfl_xor(s0, off, 64);
                s1 += __shfl_xor(s1, off, 64);
                d0 += __shfl_xor(d0, off, 64);
                d1 += __shfl_xor(d1, off, 64);
            }
            if (lane == 0){
                cvec[h] = s0; cvec[4 + h] = s1; cvec[8 + h] = d0; cvec[12 + h] = d1;
            }
        }
    }
}

// merged: blocks 0..255 bucket histogram; blocks 256..263 pack W2 fragments.
__global__ void k_histW(const int* __restrict__ dst, int E, int* bcnt,
                        const float* __restrict__ W2, uint4* __restrict__ w2frag){
    __shared__ int bh[NBKT_MAX];
    if (blockIdx.x < 256){
        for (int b = threadIdx.x; b < NBKT_MAX; b += blockDim.x) bh[b] = 0;
        __syncthreads();
        int stride = 256 * blockDim.x;
        for (int i = blockIdx.x * blockDim.x + threadIdx.x; i < E; i += stride)
            atomicAdd(&bh[dst[i] >> BK_SH], 1);
        __syncthreads();
        for (int b = threadIdx.x; b < NBKT_MAX; b += blockDim.x)
            if (bh[b]) atomicAdd(&bcnt[b], bh[b]);
    } else {
        int t = (blockIdx.x - 256) * 256 + threadIdx.x;
        if (t < 2048){
            int lane = t & 63, c = (t >> 6) & 3, s = t >> 8;
            union { uint4 u; _Float16 h[8]; } o;
#pragma unroll
            for (int e = 0; e < 8; e++){
                int k = 32 * s + 4 * (lane >> 4) + (e & 3) + 16 * (e >> 2);
                int col = 16 * c + (lane & 15);
                o.h[e] = (_Float16)W2[k * 64 + col];
            }
            w2frag[t] = o.u;
        }
    }
}

// exclusive scan of bucket counts -> bucket bases + partition cursors.
__global__ void k_bscan(const int* __restrict__ bcnt, int* bbase, int* bcursor){
    __shared__ int sh[NBKT_MAX];
    int t = threadIdx.x;     // 512 threads
    int v = bcnt[t];
    sh[t] = v;
    __syncthreads();
    for (int off = 1; off < NBKT_MAX; off <<= 1){
        int u = (t >= off) ? sh[t - off] : 0;
        __syncthreads();
        sh[t] += u;
        __syncthreads();
    }
    bbase[t] = sh[t] - v;
    bcursor[t] = sh[t] - v;
    if (t == NBKT_MAX - 1) bbase[NBKT_MAX] = sh[t];
}

// staged partition: per-tile LDS bucket count -> one global reserve per
// (block,bucket) -> scatter packed u32 (dloc<<17|src) into block-private runs.
__global__ void __launch_bounds__(256)
k_part(const int* __restrict__ src, const int* __restrict__ dst, int E,
       int* bcursor, unsigned int* __restrict__ tmp){
    __shared__ int bh[NBKT_MAX];
    __shared__ int gbl[NBKT_MAX];
    int tid = threadIdx.x;
    int base = blockIdx.x * PART_T;
    for (int b = tid; b < NBKT_MAX; b += 256) bh[b] = 0;
    __syncthreads();
#pragma unroll
    for (int r = 0; r < PART_T / 256; r++){
        int i = base + r * 256 + tid;
        if (i < E) atomicAdd(&bh[dst[i] >> BK_SH], 1);
    }
    __syncthreads();
    for (int b = tid; b < NBKT_MAX; b += 256){
        int c = bh[b];
        gbl[b] = c ? atomicAdd(&bcursor[b], c) : 0;
        bh[b] = 0;
    }
    __syncthreads();
#pragma unroll
    for (int r = 0; r < PART_T / 256; r++){
        int i = base + r * 256 + tid;
        if (i < E){
            int s = src[i], d = dst[i];
            int b = d >> BK_SH;
            int rank = atomicAdd(&bh[b], 1);
            tmp[(size_t)(gbl[b] + rank)] =
                ((unsigned)(d & ((1 << BK_SH) - 1)) << 17) | (unsigned)s;
        }
    }
}

// per-bucket CSR emit, deriving per-node offs locally:
// offs[n] = bbase[b] + n0 + excl_scan_local(deg_local+1)
__global__ void __launch_bounds__(256)
k_csr2(const unsigned int* __restrict__ tmp, const int* __restrict__ bbase,
       int N, int Et, int* __restrict__ offs, int* __restrict__ ssrc){
    __shared__ int degl[256];
    __shared__ int rc[256];
    __shared__ int scan[256];
    __shared__ int ofl[256];
    int b = blockIdx.x, tid = threadIdx.x;
    int n0 = b << BK_SH;
    int nloc = min(256, N - n0);
    degl[tid] = 0; rc[tid] = 0;
    __syncthreads();
    int beg = bbase[b], cnt = bbase[b + 1] - beg;
    for (int i = tid; i < cnt; i += 256)
        atomicAdd(&degl[tmp[beg + i] >> 17], 1);
    __syncthreads();
    int v = (tid < nloc) ? degl[tid] + 1 : 0;
    scan[tid] = v;
    __syncthreads();
    for (int off = 1; off < 256; off <<= 1){
        int u = (tid >= off) ? scan[tid - off] : 0;
        __syncthreads();
        scan[tid] += u;
        __syncthreads();
    }
    int base = beg + n0;
    if (tid < nloc){
        int o = base + scan[tid] - v;   // exclusive
        ofl[tid] = o;
        offs[n0 + tid] = o;
        ssrc[o] = n0 + tid;             // self-loop first
    }
    if (b == 0 && tid == 0) offs[N] = Et;
    __syncthreads();
    for (int i = tid; i < cnt; i += 256){
        unsigned int e = tmp[beg + i];
        int dloc = (int)(e >> 17);
        int s = (int)(e & 0x1FFFFu);
        int pos = ofl[dloc] + 1 + atomicAdd(&rc[dloc], 1);
        ssrc[pos] = s;
    }
}

// layer-1 aggregation via rank-2 trick, 4 LANES PER NODE (stride-4 edge split,
// 2-step shfl_xor reduce of the 12 scalars). 400k threads = 24 waves/CU.
__global__ void k_agg1s(const float* __restrict__ x, const int* __restrict__ offs,
                        const int* __restrict__ ssrc, const float* __restrict__ cvec,
                        int N, float4* Sa, float4* Sb, float4* Sc){
    int t = blockIdx.x * blockDim.x + threadIdx.x;
    int n = t >> 2, sub = t & 3;
    if (n >= N) return;
    float4 cs0 = ((const float4*)cvec)[0];
    float4 cs1 = ((const float4*)cvec)[1];
    float4 cd0 = ((const float4*)cvec)[2];
    float4 cd1 = ((const float4*)cvec)[3];
    float c0[4] = {cs0.x, cs0.y, cs0.z, cs0.w};
    float c1[4] = {cs1.x, cs1.y, cs1.z, cs1.w};
    float2 xn = ((const float2*)x)[n];
    float ad[4] = {xn.x*cd0.x + xn.y*cd1.x, xn.x*cd0.y + xn.y*cd1.y,
                   xn.x*cd0.z + xn.y*cd1.z, xn.x*cd0.w + xn.y*cd1.w};
    float A0[4] = {0,0,0,0}, A1[4] = {0,0,0,0}, D[4] = {0,0,0,0};
    int beg = offs[n], end = offs[n + 1];
    int j = beg + sub;
    for (; j + 12 < end; j += 16){     // 4 edges/lane/iter (stride 4)
        int si[4] = {ssrc[j], ssrc[j+4], ssrc[j+8], ssrc[j+12]};
        float2 xs[4];
#pragma unroll
        for (int u = 0; u < 4; u++) xs[u] = ((const float2*)x)[si[u]];
#pragma unroll
        for (int h = 0; h < HEADS; h++){
#pragma unroll
            for (int u = 0; u < 4; u++){
                float w = __expf(lrelu(xs[u].x * c0[h] + xs[u].y * c1[h] + ad[h]));
                A0[h] += w * xs[u].x;
                A1[h] += w * xs[u].y;
                D[h]  += w;
            }
        }
    }
    for (; j < end; j += 4){
        int s = ssrc[j];
        float2 xs = ((const float2*)x)[s];
#pragma unroll
        for (int h = 0; h < HEADS; h++){
            float e = xs.x * c0[h] + xs.y * c1[h] + ad[h];
            float w = __expf(lrelu(e));
            A0[h] += w * xs.x;
            A1[h] += w * xs.y;
            D[h]  += w;
        }
    }
    // reduce across the 4 lanes of this node
#pragma unroll
    for (int h = 0; h < HEADS; h++){
        A0[h] += __shfl_xor(A0[h], 1, 64); A0[h] += __shfl_xor(A0[h], 2, 64);
        A1[h] += __shfl_xor(A1[h], 1, 64); A1[h] += __shfl_xor(A1[h], 2, 64);
        D[h]  += __shfl_xor(D[h],  1, 64); D[h]  += __shfl_xor(D[h],  2, 64);
    }
    if (sub == 0){
        Sa[n] = make_float4(A0[0], A0[1], A0[2], A0[3]);
        Sb[n] = make_float4(A1[0], A1[1], A1[2], A1[3]);
        Sc[n] = make_float4(D[0],  D[1],  D[2],  D[3]);
    }
}

// Fused MFMA layer-2 GEMM: A-fragments (h1 rows) computed in-register from
// the 12 per-node scalars; W1/b1 + W2 fragments staged in LDS.
__global__ void __launch_bounds__(256)
k_mfma(const float4* __restrict__ Sa4, const float4* __restrict__ Sb4,
       const float4* __restrict__ Sc4, const float* __restrict__ W1,
       const float* __restrict__ b1, const uint4* __restrict__ w2frag,
       const float* __restrict__ as2, const float* __restrict__ ad2,
       int N, __half* __restrict__ xh2, float* __restrict__ asrc,
       float* __restrict__ adst){
    __shared__ uint4 w2s[2048];                      // 32 KB B fragments
    __shared__ float4 w1aS[64], w1bS[64], b1S[64];   // 3 KB W1 rows + b1
    int tid = threadIdx.x;
    for (int i = tid; i < 2048; i += 256) w2s[i] = w2frag[i];
    if (tid < 64){
        w1aS[tid] = ((const float4*)W1)[tid];
        w1bS[tid] = ((const float4*)W1)[tid + 64];
        b1S[tid]  = ((const float4*)b1)[tid];
    }
    __syncthreads();

    int lane = tid & 63, wv = tid >> 6;
    int r = lane & 15, g = lane >> 4;
    float asw0 = as2[r], asw1 = as2[16 + r], asw2 = as2[32 + r], asw3 = as2[48 + r];
    float adw0 = ad2[r], adw1 = ad2[16 + r], adw2 = ad2[32 + r], adw3 = ad2[48 + r];

    int ntiles = (N + 15) >> 4;
    for (int t = blockIdx.x * 4 + wv; t < ntiles; t += gridDim.x * 4){
        int base = t << 4;
        int nodeA = min(base + r, N - 1);
        float4 sa = Sa4[nodeA], sb = Sb4[nodeA], sc = Sc4[nodeA];
        float rdv0 = 1.0f / sc.x, rdv1 = 1.0f / sc.y;
        float rdv2 = 1.0f / sc.z, rdv3 = 1.0f / sc.w;
        f32x4 ac0 = {0.f,0.f,0.f,0.f}, ac1 = {0.f,0.f,0.f,0.f};
        f32x4 ac2 = {0.f,0.f,0.f,0.f}, ac3 = {0.f,0.f,0.f,0.f};
#pragma unroll
        for (int s = 0; s < 8; s++){
            const int head = s >> 1;                 // compile-time
            float A0 = head == 0 ? sa.x : head == 1 ? sa.y : head == 2 ? sa.z : sa.w;
            float A1 = head == 0 ? sb.x : head == 1 ? sb.y : head == 2 ? sb.z : sb.w;
            float rd = head == 0 ? rdv0 : head == 1 ? rdv1 : head == 2 ? rdv2 : rdv3;
            int q0 = 8 * s + g;
            float4 w0lo = w1aS[q0], w0hi = w1aS[q0 + 4];
            float4 w1lo = w1bS[q0], w1hi = w1bS[q0 + 4];
            float4 blo  = b1S[q0],  bhi  = b1S[q0 + 4];
            union { uint4 u; f16x8 f; _Float16 h[8]; } a;
            a.h[0] = (_Float16)elu_((A0 * w0lo.x + A1 * w1lo.x) * rd + blo.x);
            a.h[1] = (_Float16)elu_((A0 * w0lo.y + A1 * w1lo.y) * rd + blo.y);
            a.h[2] = (_Float16)elu_((A0 * w0lo.z + A1 * w1lo.z) * rd + blo.z);
            a.h[3] = (_Float16)elu_((A0 * w0lo.w + A1 * w1lo.w) * rd + blo.w);
            a.h[4] = (_Float16)elu_((A0 * w0hi.x + A1 * w1hi.x) * rd + bhi.x);
            a.h[5] = (_Float16)elu_((A0 * w0hi.y + A1 * w1hi.y) * rd + bhi.y);
            a.h[6] = (_Float16)elu_((A0 * w0hi.z + A1 * w1hi.z) * rd + bhi.z);
            a.h[7] = (_Float16)elu_((A0 * w0hi.w + A1 * w1hi.w) * rd + bhi.w);
            union { uint4 u; f16x8 f; } b0, b1x, b2, b3;
            b0.u  = w2s[(s * 4 + 0) * 64 + lane];
            b1x.u = w2s[(s * 4 + 1) * 64 + lane];
            b2.u  = w2s[(s * 4 + 2) * 64 + lane];
            b3.u  = w2s[(s * 4 + 3) * 64 + lane];
            ac0 = __builtin_amdgcn_mfma_f32_16x16x32_f16(a.f, b0.f,  ac0, 0, 0, 0);
            ac1 = __builtin_amdgcn_mfma_f32_16x16x32_f16(a.f, b1x.f, ac1, 0, 0, 0);
            ac2 = __builtin_amdgcn_mfma_f32_16x16x32_f16(a.f, b2.f,  ac2, 0, 0, 0);
            ac3 = __builtin_amdgcn_mfma_f32_16x16x32_f16(a.f, b3.f,  ac3, 0, 0, 0);
        }
        float ps0 = 0.f, ps1 = 0.f, ps2 = 0.f, ps3 = 0.f;
        float pd0 = 0.f, pd1 = 0.f, pd2 = 0.f, pd3 = 0.f;
#pragma unroll
        for (int reg = 0; reg < 4; reg++){
            int node = base + 4 * g + reg;
            if (node < N){
                size_t rowb = (size_t)node * 64;
                xh2[rowb +      r] = __float2half(ac0[reg]);
                xh2[rowb + 16 + r] = __float2half(ac1[reg]);
                xh2[rowb + 32 + r] = __float2half(ac2[reg]);
                xh2[rowb + 48 + r] = __float2half(ac3[reg]);
            }
            float ps = ac0[reg]*asw0 + ac1[reg]*asw1 + ac2[reg]*asw2 + ac3[reg]*asw3;
            float pd = ac0[reg]*adw0 + ac1[reg]*adw1 + ac2[reg]*adw2 + ac3[reg]*adw3;
            if (reg == 0){ ps0 = ps; pd0 = pd; }
            else if (reg == 1){ ps1 = ps; pd1 = pd; }
            else if (reg == 2){ ps2 = ps; pd2 = pd; }
            else { ps3 = ps; pd3 = pd; }
        }
#pragma unroll
        for (int m = 1; m < 16; m <<= 1){
            ps0 += __shfl_xor(ps0, m, 64); pd0 += __shfl_xor(pd0, m, 64);
            ps1 += __shfl_xor(ps1, m, 64); pd1 += __shfl_xor(pd1, m, 64);
            ps2 += __shfl_xor(ps2, m, 64); pd2 += __shfl_xor(pd2, m, 64);
            ps3 += __shfl_xor(ps3, m, 64); pd3 += __shfl_xor(pd3, m, 64);
        }
        if (r == 0){
            int nb = base + 4 * g;
            if (nb     < N){ asrc[nb    ] = ps0; adst[nb    ] = pd0; }
            if (nb + 1 < N){ asrc[nb + 1] = ps1; adst[nb + 1] = pd1; }
            if (nb + 2 < N){ asrc[nb + 2] = ps2; adst[nb + 2] = pd2; }
            if (nb + 3 < N){ asrc[nb + 3] = ps3; adst[nb + 3] = pd3; }
        }
    }
}

// layer-2 aggregation + mean pool. COOPERATIVE GATHER: 16 contiguous edge
// indices loaded in ONE instr (lane&15), one gathered asrc load, ONE exp for
// all 16 edges (replicated x4), s/w distributed via shfl. Rows stay per-lane
// half2 dwords (half 0 -> even edges, half 1 -> odd).
__global__ void k_agg2p(const __half* __restrict__ xh2, const float* __restrict__ asrc,
                        const float* __restrict__ adst, const int* __restrict__ offs,
                        const int* __restrict__ ssrc, const float* __restrict__ b2,
                        const int* __restrict__ batch, int N,
                        float* sums, int* counts){
    int tid = threadIdx.x;
    int lane = tid & 63, wv = tid >> 6;  // 4 waves/block
    int c = lane & 31;     // channel pair: channels 2c, 2c+1
    int half = lane >> 5;  // 0 or 1
    int l16 = lane & 15;
    int wid = blockIdx.x * 4 + wv;
    int nw = gridDim.x * 4;
    int chunk = (N + nw - 1) / nw;
    int beg = wid * chunk, end = min(beg + chunk, N);
    if (beg >= end) return;
    const unsigned int* xrow = (const unsigned int*)xh2;   // 32 dwords per row
    float b2a = b2[2 * c], b2b = b2[2 * c + 1];
    float pacc0 = 0.f, pacc1 = 0.f; int pcnt = 0; int cur = batch[beg];
    for (int n = beg; n < end; n++){
        float ad = adst[n];
        float acc0 = 0.f, acc1 = 0.f, den = 0.f;
        int e0 = offs[n], e1 = offs[n + 1];
        int j = e0;
        for (; j + 16 <= e1; j += 16){
            int sA = ssrc[j + l16];                 // 1 VMEM: 16 consecutive
            float wA = __expf(lrelu(asrc[sA] + ad)); // 1 gather + 1 exp (x4 repl)
            int su[8];
#pragma unroll
            for (int u = 0; u < 8; u++) su[u] = __shfl(sA, 2 * u + half, 64);
            unsigned int rv[8];
#pragma unroll
            for (int u = 0; u < 8; u++) rv[u] = xrow[(size_t)su[u] * 32 + c];
#pragma unroll
            for (int u = 0; u < 8; u++){
                float wu = __shfl(wA, 2 * u + half, 64);
                float2 f = __half22float2(*(const __half2*)&rv[u]);
                acc0 += wu * f.x;
                acc1 += wu * f.y;
                den  += wu;
            }
        }
        if (j + 8 <= e1){                          // 8-edge block
            int sA = ssrc[j + (lane & 7)];
            float wA = __expf(lrelu(asrc[sA] + ad));
            int su[4];
#pragma unroll
            for (int u = 0; u < 4; u++) su[u] = __shfl(sA, 2 * u + half, 64);
            unsigned int rv[4];
#pragma unroll
            for (int u = 0; u < 4; u++) rv[u] = xrow[(size_t)su[u] * 32 + c];
#pragma unroll
            for (int u = 0; u < 4; u++){
                float wu = __shfl(wA, 2 * u + half, 64);
                float2 f = __half22float2(*(const __half2*)&rv[u]);
                acc0 += wu * f.x;
                acc1 += wu * f.y;
                den  += wu;
            }
            j += 8;
        }
        for (; j + 2 <= e1; j += 2){               // pair
            int s = ssrc[j + half];
            float a = asrc[s];
            unsigned int rr = xrow[(size_t)s * 32 + c];
            float w = __expf(lrelu(a + ad));
            float2 f = __half22float2(*(const __half2*)&rr);
            acc0 += w * f.x;
            acc1 += w * f.y;
            den  += w;
        }
        if (j < e1){                               // odd tail
            int s = ssrc[j];
            float w = (half == 0) ? __expf(lrelu(asrc[s] + ad)) : 0.f;
            unsigned int rr = xrow[(size_t)s * 32 + c];
            float2 f = __half22float2(*(const __half2*)&rr);
            acc0 += w * f.x;
            acc1 += w * f.y;
            den  += w;
        }
        acc0 += __shfl_xor(acc0, 32, 64);
        acc1 += __shfl_xor(acc1, 32, 64);
        den  += __shfl_xor(den, 32, 64);
        float h2a = elu_(acc0 / den + b2a);
        float h2b = elu_(acc1 / den + b2b);
        int g = batch[n];
        if (g != cur){
            if (half == 0){
                atomicAdd(&sums[cur * HID + 2 * c    ], pacc0);
                atomicAdd(&sums[cur * HID + 2 * c + 1], pacc1);
            }
            if (lane == 0) atomicAdd(&counts[cur], pcnt);
            pacc0 = 0.f; pacc1 = 0.f; pcnt = 0; cur = g;
        }
        pacc0 += h2a; pacc1 += h2b; pcnt++;
    }
    if (half == 0){
        atomicAdd(&sums[cur * HID + 2 * c    ], pacc0);
        atomicAdd(&sums[cur * HID + 2 * c + 1], pacc1);
    }
    if (lane == 0) atomicAdd(&counts[cur], pcnt);
}

__global__ void k_final(const float* __restrict__ sums, const int* __restrict__ counts,
                        const float* __restrict__ Wl, const float* __restrict__ bl,
                        float* out){
    int t = threadIdx.x;
    if (t >= GR * 2) return;
    int g = t >> 1, task = t & 1;
    float c = (float)max(counts[g], 1);
    float acc = 0.f;
#pragma unroll
    for (int k = 0; k < HID; k++)
        acc += (sums[g * HID + k] / c) * Wl[k * 2 + task];
    out[t] = acc + bl[task];
}

extern "C" void kernel_launch(void* const* d_in, const int* in_sizes, int n_in,
                              void* d_out, int out_size, void* d_ws, size_t ws_size,
                              hipStream_t stream) {
    const float* x    = (const float*)d_in[0];
    const int*   ei   = (const int*)  d_in[1];
    const int*   batch= (const int*)  d_in[2];
    const float* W1   = (const float*)d_in[3];
    const float* as1  = (const float*)d_in[4];
    const float* ad1  = (const float*)d_in[5];
    const float* b1   = (const float*)d_in[6];
    const float* W2   = (const float*)d_in[7];
    const float* as2  = (const float*)d_in[8];
    const float* ad2  = (const float*)d_in[9];
    const float* b2   = (const float*)d_in[10];
    const float* Wl   = (const float*)d_in[11];
    const float* bl   = (const float*)d_in[12];
    float* out = (float*)d_out;

    int N  = in_sizes[0] / 2;
    int E  = in_sizes[1] / 2;
    int Et = E + N;
    const int* srcp = ei;
    const int* dstp = ei + E;

    char* p = (char*)d_ws;
    auto alloc = [&](size_t bytes)->char* {
        char* r = p; p += (bytes + 255) & ~(size_t)255; return r;
    };
    int*    offs   = (int*)   alloc((size_t)(N + 1) * 4);
    int*    bcnt   = (int*)   alloc(NBKT_MAX * 4);
    int*    bbase  = (int*)   alloc((NBKT_MAX + 1) * 4);
    int*    bcursor= (int*)   alloc(NBKT_MAX * 4);
    int*    ssrc   = (int*)   alloc((size_t)Et * 4);
    unsigned int* tmp = (unsigned int*)alloc((size_t)E * 4);
    float*  cvec   = (float*) alloc(16 * 4);
    float4* Sa     = (float4*)alloc((size_t)N * 16);
    float4* Sb     = (float4*)alloc((size_t)N * 16);
    float4* Sc     = (float4*)alloc((size_t)N * 16);
    float*  asrc2  = (float*) alloc((size_t)N * 4);
    float*  adst2  = (float*) alloc((size_t)N * 4);
    float*  sums   = (float*) alloc((size_t)GR * HID * 4);
    int*    counts = (int*)   alloc((size_t)GR * 4);
    uint4*  w2frag = (uint4*) alloc(2048 * 16);
    __half* xh2    = (__half*)alloc((size_t)N * 64 * 2);

    int nbkt = (N + 255) >> BK_SH;

    k_init <<<16, 256, 0, stream>>>(sums, counts, bcnt, W1, as1, ad1, cvec);
    k_histW<<<264, 256, 0, stream>>>(dstp, E, bcnt, W2, w2frag);
    k_bscan<<<1, NBKT_MAX, 0, stream>>>(bcnt, bbase, bcursor);
    k_part <<<(E + PART_T - 1) / PART_T, 256, 0, stream>>>(srcp, dstp, E, bcursor, tmp);
    k_csr2 <<<nbkt, 256, 0, stream>>>(tmp, bbase, N, Et, offs, ssrc);

    k_agg1s<<<((N * 4) + 255) / 256, 256, 0, stream>>>(x, offs, ssrc, cvec, N, Sa, Sb, Sc);
    k_mfma <<<1024, 256, 0, stream>>>(Sa, Sb, Sc, W1, b1, w2frag, as2, ad2,
                                      N, xh2, asrc2, adst2);
    k_agg2p<<<2048, 256, 0, stream>>>(xh2, asrc2, adst2, offs, ssrc, b2,
                                      batch, N, sums, counts);
    k_final<<<1, 128, 0, stream>>>(sums, counts, Wl, bl, out);
}

// Round 13
// 212.730 us; speedup vs baseline: 1.0155x; 1.0155x over previous
//
#include <hip/hip_runtime.h>
#include <hip/hip_fp16.h>
#include <math.h>

#define HID 64
#define HEADS 4
#define GR 64
#define NEG 0.2f
#define NBKT_MAX 512
#define BK_SH 8     // 256 nodes per bucket
#define PART_T 2048 // edges per partition tile
// tmp edge pack: (dst & 255) << 17 | src   -- requires N < 2^17 (N=100000 ok)

typedef _Float16 f16x8 __attribute__((ext_vector_type(8)));
typedef float    f32x4 __attribute__((ext_vector_type(4)));

__device__ __forceinline__ float lrelu(float v){ return v > 0.f ? v : NEG * v; }
__device__ __forceinline__ float elu_(float v){ return v > 0.f ? v : __expf(v) - 1.f; }

// zero pooled sums/counts/bucket-counts; block 0 wave 0 also computes the
// attention-projection constants cvec = [cs0(4), cs1(4), cd0(4), cd1(4)].
// (must run EVERY call: harness does not re-poison ws between timed replays)
__global__ void k_init(float* sums, int* counts, int* bcnt,
                       const float* __restrict__ W1, const float* __restrict__ as1,
                       const float* __restrict__ ad1, float* cvec){
    int i = blockIdx.x * blockDim.x + threadIdx.x;
    if (i < GR * HID) sums[i] = 0.f;
    if (i < GR) counts[i] = 0;
    if (i < NBKT_MAX) bcnt[i] = 0;
    if (blockIdx.x == 0 && threadIdx.x < 64){
        int lane = threadIdx.x;
#pragma unroll
        for (int h = 0; h < HEADS; h++){
            int j = h * HID + lane;
            float s0 = W1[j]       * as1[j];
            float s1 = W1[256 + j] * as1[j];
            float d0 = W1[j]       * ad1[j];
            float d1 = W1[256 + j] * ad1[j];
#pragma unroll
            for (int off = 32; off; off >>= 1){
                s0 += __shfl_xor(s0, off, 64);
                s1 += __shfl_xor(s1, off, 64);
                d0 += __shfl_xor(d0, off, 64);
                d1 += __shfl_xor(d1, off, 64);
            }
            if (lane == 0){
                cvec[h] = s0; cvec[4 + h] = s1; cvec[8 + h] = d0; cvec[12 + h] = d1;
            }
        }
    }
}

// merged: blocks 0..255 bucket histogram; blocks 256..263 pack W2 fragments.
__global__ void k_histW(const int* __restrict__ dst, int E, int* bcnt,
                        const float* __restrict__ W2, uint4* __restrict__ w2frag){
    __shared__ int bh[NBKT_MAX];
    if (blockIdx.x < 256){
        for (int b = threadIdx.x; b < NBKT_MAX; b += blockDim.x) bh[b] = 0;
        __syncthreads();
        int stride = 256 * blockDim.x;
        for (int i = blockIdx.x * blockDim.x + threadIdx.x; i < E; i += stride)
            atomicAdd(&bh[dst[i] >> BK_SH], 1);
        __syncthreads();
        for (int b = threadIdx.x; b < NBKT_MAX; b += blockDim.x)
            if (bh[b]) atomicAdd(&bcnt[b], bh[b]);
    } else {
        int t = (blockIdx.x - 256) * 256 + threadIdx.x;
        if (t < 2048){
            int lane = t & 63, c = (t >> 6) & 3, s = t >> 8;
            union { uint4 u; _Float16 h[8]; } o;
#pragma unroll
            for (int e = 0; e < 8; e++){
                int k = 32 * s + 4 * (lane >> 4) + (e & 3) + 16 * (e >> 2);
                int col = 16 * c + (lane & 15);
                o.h[e] = (_Float16)W2[k * 64 + col];
            }
            w2frag[t] = o.u;
        }
    }
}

// exclusive scan of bucket counts -> bucket bases + partition cursors.
__global__ void k_bscan(const int* __restrict__ bcnt, int* bbase, int* bcursor){
    __shared__ int sh[NBKT_MAX];
    int t = threadIdx.x;     // 512 threads
    int v = bcnt[t];
    sh[t] = v;
    __syncthreads();
    for (int off = 1; off < NBKT_MAX; off <<= 1){
        int u = (t >= off) ? sh[t - off] : 0;
        __syncthreads();
        sh[t] += u;
        __syncthreads();
    }
    bbase[t] = sh[t] - v;
    bcursor[t] = sh[t] - v;
    if (t == NBKT_MAX - 1) bbase[NBKT_MAX] = sh[t];
}

// staged partition: per-tile LDS bucket count -> one global reserve per
// (block,bucket) -> scatter packed u32 (dloc<<17|src) into block-private runs.
__global__ void __launch_bounds__(256)
k_part(const int* __restrict__ src, const int* __restrict__ dst, int E,
       int* bcursor, unsigned int* __restrict__ tmp){
    __shared__ int bh[NBKT_MAX];
    __shared__ int gbl[NBKT_MAX];
    int tid = threadIdx.x;
    int base = blockIdx.x * PART_T;
    for (int b = tid; b < NBKT_MAX; b += 256) bh[b] = 0;
    __syncthreads();
#pragma unroll
    for (int r = 0; r < PART_T / 256; r++){
        int i = base + r * 256 + tid;
        if (i < E) atomicAdd(&bh[dst[i] >> BK_SH], 1);
    }
    __syncthreads();
    for (int b = tid; b < NBKT_MAX; b += 256){
        int c = bh[b];
        gbl[b] = c ? atomicAdd(&bcursor[b], c) : 0;
        bh[b] = 0;
    }
    __syncthreads();
#pragma unroll
    for (int r = 0; r < PART_T / 256; r++){
        int i = base + r * 256 + tid;
        if (i < E){
            int s = src[i], d = dst[i];
            int b = d >> BK_SH;
            int rank = atomicAdd(&bh[b], 1);
            tmp[(size_t)(gbl[b] + rank)] =
                ((unsigned)(d & ((1 << BK_SH) - 1)) << 17) | (unsigned)s;
        }
    }
}

// per-bucket CSR emit, deriving per-node offs locally:
// offs[n] = bbase[b] + n0 + excl_scan_local(deg_local+1)
__global__ void __launch_bounds__(256)
k_csr2(const unsigned int* __restrict__ tmp, const int* __restrict__ bbase,
       int N, int Et, int* __restrict__ offs, int* __restrict__ ssrc){
    __shared__ int degl[256];
    __shared__ int rc[256];
    __shared__ int scan[256];
    __shared__ int ofl[256];
    int b = blockIdx.x, tid = threadIdx.x;
    int n0 = b << BK_SH;
    int nloc = min(256, N - n0);
    degl[tid] = 0; rc[tid] = 0;
    __syncthreads();
    int beg = bbase[b], cnt = bbase[b + 1] - beg;
    for (int i = tid; i < cnt; i += 256)
        atomicAdd(&degl[tmp[beg + i] >> 17], 1);
    __syncthreads();
    int v = (tid < nloc) ? degl[tid] + 1 : 0;
    scan[tid] = v;
    __syncthreads();
    for (int off = 1; off < 256; off <<= 1){
        int u = (tid >= off) ? scan[tid - off] : 0;
        __syncthreads();
        scan[tid] += u;
        __syncthreads();
    }
    int base = beg + n0;
    if (tid < nloc){
        int o = base + scan[tid] - v;   // exclusive
        ofl[tid] = o;
        offs[n0 + tid] = o;
        ssrc[o] = n0 + tid;             // self-loop first
    }
    if (b == 0 && tid == 0) offs[N] = Et;
    __syncthreads();
    for (int i = tid; i < cnt; i += 256){
        unsigned int e = tmp[beg + i];
        int dloc = (int)(e >> 17);
        int s = (int)(e & 0x1FFFFu);
        int pos = ofl[dloc] + 1 + atomicAdd(&rc[dloc], 1);
        ssrc[pos] = s;
    }
}

// layer-1 aggregation via rank-2 trick, 4 lanes per node (stride-4 edge split,
// 2-step shfl_xor reduce of the 12 scalars). 400k threads = 24 waves/CU.
__global__ void k_agg1s(const float* __restrict__ x, const int* __restrict__ offs,
                        const int* __restrict__ ssrc, const float* __restrict__ cvec,
                        int N, float4* Sa, float4* Sb, float4* Sc){
    int t = blockIdx.x * blockDim.x + threadIdx.x;
    int n = t >> 2, sub = t & 3;
    if (n >= N) return;
    float4 cs0 = ((const float4*)cvec)[0];
    float4 cs1 = ((const float4*)cvec)[1];
    float4 cd0 = ((const float4*)cvec)[2];
    float4 cd1 = ((const float4*)cvec)[3];
    float c0[4] = {cs0.x, cs0.y, cs0.z, cs0.w};
    float c1[4] = {cs1.x, cs1.y, cs1.z, cs1.w};
    float2 xn = ((const float2*)x)[n];
    float ad[4] = {xn.x*cd0.x + xn.y*cd1.x, xn.x*cd0.y + xn.y*cd1.y,
                   xn.x*cd0.z + xn.y*cd1.z, xn.x*cd0.w + xn.y*cd1.w};
    float A0[4] = {0,0,0,0}, A1[4] = {0,0,0,0}, D[4] = {0,0,0,0};
    int beg = offs[n], end = offs[n + 1];
    int j = beg + sub;
    for (; j + 12 < end; j += 16){     // 4 edges/lane/iter (stride 4)
        int si[4] = {ssrc[j], ssrc[j+4], ssrc[j+8], ssrc[j+12]};
        float2 xs[4];
#pragma unroll
        for (int u = 0; u < 4; u++) xs[u] = ((const float2*)x)[si[u]];
#pragma unroll
        for (int h = 0; h < HEADS; h++){
#pragma unroll
            for (int u = 0; u < 4; u++){
                float w = __expf(lrelu(xs[u].x * c0[h] + xs[u].y * c1[h] + ad[h]));
                A0[h] += w * xs[u].x;
                A1[h] += w * xs[u].y;
                D[h]  += w;
            }
        }
    }
    for (; j < end; j += 4){
        int s = ssrc[j];
        float2 xs = ((const float2*)x)[s];
#pragma unroll
        for (int h = 0; h < HEADS; h++){
            float e = xs.x * c0[h] + xs.y * c1[h] + ad[h];
            float w = __expf(lrelu(e));
            A0[h] += w * xs.x;
            A1[h] += w * xs.y;
            D[h]  += w;
        }
    }
#pragma unroll
    for (int h = 0; h < HEADS; h++){
        A0[h] += __shfl_xor(A0[h], 1, 64); A0[h] += __shfl_xor(A0[h], 2, 64);
        A1[h] += __shfl_xor(A1[h], 1, 64); A1[h] += __shfl_xor(A1[h], 2, 64);
        D[h]  += __shfl_xor(D[h],  1, 64); D[h]  += __shfl_xor(D[h],  2, 64);
    }
    if (sub == 0){
        Sa[n] = make_float4(A0[0], A0[1], A0[2], A0[3]);
        Sb[n] = make_float4(A1[0], A1[1], A1[2], A1[3]);
        Sc[n] = make_float4(D[0],  D[1],  D[2],  D[3]);
    }
}

// Fused MFMA layer-2 GEMM: A-fragments (h1 rows) computed in-register from
// the 12 per-node scalars; W1/b1 + W2 fragments staged in LDS.
__global__ void __launch_bounds__(256)
k_mfma(const float4* __restrict__ Sa4, const float4* __restrict__ Sb4,
       const float4* __restrict__ Sc4, const float* __restrict__ W1,
       const float* __restrict__ b1, const uint4* __restrict__ w2frag,
       const float* __restrict__ as2, const float* __restrict__ ad2,
       int N, __half* __restrict__ xh2, float* __restrict__ asrc,
       float* __restrict__ adst){
    __shared__ uint4 w2s[2048];                      // 32 KB B fragments
    __shared__ float4 w1aS[64], w1bS[64], b1S[64];   // 3 KB W1 rows + b1
    int tid = threadIdx.x;
    for (int i = tid; i < 2048; i += 256) w2s[i] = w2frag[i];
    if (tid < 64){
        w1aS[tid] = ((const float4*)W1)[tid];
        w1bS[tid] = ((const float4*)W1)[tid + 64];
        b1S[tid]  = ((const float4*)b1)[tid];
    }
    __syncthreads();

    int lane = tid & 63, wv = tid >> 6;
    int r = lane & 15, g = lane >> 4;
    float asw0 = as2[r], asw1 = as2[16 + r], asw2 = as2[32 + r], asw3 = as2[48 + r];
    float adw0 = ad2[r], adw1 = ad2[16 + r], adw2 = ad2[32 + r], adw3 = ad2[48 + r];

    int ntiles = (N + 15) >> 4;
    for (int t = blockIdx.x * 4 + wv; t < ntiles; t += gridDim.x * 4){
        int base = t << 4;
        int nodeA = min(base + r, N - 1);
        float4 sa = Sa4[nodeA], sb = Sb4[nodeA], sc = Sc4[nodeA];
        float rdv0 = 1.0f / sc.x, rdv1 = 1.0f / sc.y;
        float rdv2 = 1.0f / sc.z, rdv3 = 1.0f / sc.w;
        f32x4 ac0 = {0.f,0.f,0.f,0.f}, ac1 = {0.f,0.f,0.f,0.f};
        f32x4 ac2 = {0.f,0.f,0.f,0.f}, ac3 = {0.f,0.f,0.f,0.f};
#pragma unroll
        for (int s = 0; s < 8; s++){
            const int head = s >> 1;                 // compile-time
            float A0 = head == 0 ? sa.x : head == 1 ? sa.y : head == 2 ? sa.z : sa.w;
            float A1 = head == 0 ? sb.x : head == 1 ? sb.y : head == 2 ? sb.z : sb.w;
            float rd = head == 0 ? rdv0 : head == 1 ? rdv1 : head == 2 ? rdv2 : rdv3;
            int q0 = 8 * s + g;
            float4 w0lo = w1aS[q0], w0hi = w1aS[q0 + 4];
            float4 w1lo = w1bS[q0], w1hi = w1bS[q0 + 4];
            float4 blo  = b1S[q0],  bhi  = b1S[q0 + 4];
            union { uint4 u; f16x8 f; _Float16 h[8]; } a;
            a.h[0] = (_Float16)elu_((A0 * w0lo.x + A1 * w1lo.x) * rd + blo.x);
            a.h[1] = (_Float16)elu_((A0 * w0lo.y + A1 * w1lo.y) * rd + blo.y);
            a.h[2] = (_Float16)elu_((A0 * w0lo.z + A1 * w1lo.z) * rd + blo.z);
            a.h[3] = (_Float16)elu_((A0 * w0lo.w + A1 * w1lo.w) * rd + blo.w);
            a.h[4] = (_Float16)elu_((A0 * w0hi.x + A1 * w1hi.x) * rd + bhi.x);
            a.h[5] = (_Float16)elu_((A0 * w0hi.y + A1 * w1hi.y) * rd + bhi.y);
            a.h[6] = (_Float16)elu_((A0 * w0hi.z + A1 * w1hi.z) * rd + bhi.z);
            a.h[7] = (_Float16)elu_((A0 * w0hi.w + A1 * w1hi.w) * rd + bhi.w);
            union { uint4 u; f16x8 f; } b0, b1x, b2, b3;
            b0.u  = w2s[(s * 4 + 0) * 64 + lane];
            b1x.u = w2s[(s * 4 + 1) * 64 + lane];
            b2.u  = w2s[(s * 4 + 2) * 64 + lane];
            b3.u  = w2s[(s * 4 + 3) * 64 + lane];
            ac0 = __builtin_amdgcn_mfma_f32_16x16x32_f16(a.f, b0.f,  ac0, 0, 0, 0);
            ac1 = __builtin_amdgcn_mfma_f32_16x16x32_f16(a.f, b1x.f, ac1, 0, 0, 0);
            ac2 = __builtin_amdgcn_mfma_f32_16x16x32_f16(a.f, b2.f,  ac2, 0, 0, 0);
            ac3 = __builtin_amdgcn_mfma_f32_16x16x32_f16(a.f, b3.f,  ac3, 0, 0, 0);
        }
        float ps0 = 0.f, ps1 = 0.f, ps2 = 0.f, ps3 = 0.f;
        float pd0 = 0.f, pd1 = 0.f, pd2 = 0.f, pd3 = 0.f;
#pragma unroll
        for (int reg = 0; reg < 4; reg++){
            int node = base + 4 * g + reg;
            if (node < N){
                size_t rowb = (size_t)node * 64;
                xh2[rowb +      r] = __float2half(ac0[reg]);
                xh2[rowb + 16 + r] = __float2half(ac1[reg]);
                xh2[rowb + 32 + r] = __float2half(ac2[reg]);
                xh2[rowb + 48 + r] = __float2half(ac3[reg]);
            }
            float ps = ac0[reg]*asw0 + ac1[reg]*asw1 + ac2[reg]*asw2 + ac3[reg]*asw3;
            float pd = ac0[reg]*adw0 + ac1[reg]*adw1 + ac2[reg]*adw2 + ac3[reg]*adw3;
            if (reg == 0){ ps0 = ps; pd0 = pd; }
            else if (reg == 1){ ps1 = ps; pd1 = pd; }
            else if (reg == 2){ ps2 = ps; pd2 = pd; }
            else { ps3 = ps; pd3 = pd; }
        }
#pragma unroll
        for (int m = 1; m < 16; m <<= 1){
            ps0 += __shfl_xor(ps0, m, 64); pd0 += __shfl_xor(pd0, m, 64);
            ps1 += __shfl_xor(ps1, m, 64); pd1 += __shfl_xor(pd1, m, 64);
            ps2 += __shfl_xor(ps2, m, 64); pd2 += __shfl_xor(pd2, m, 64);
            ps3 += __shfl_xor(ps3, m, 64); pd3 += __shfl_xor(pd3, m, 64);
        }
        if (r == 0){
            int nb = base + 4 * g;
            if (nb     < N){ asrc[nb    ] = ps0; adst[nb    ] = pd0; }
            if (nb + 1 < N){ asrc[nb + 1] = ps1; adst[nb + 1] = pd1; }
            if (nb + 2 < N){ asrc[nb + 2] = ps2; adst[nb + 2] = pd2; }
            if (nb + 3 < N){ asrc[nb + 3] = ps3; adst[nb + 3] = pd3; }
        }
    }
}

// layer-2 aggregation + mean pool, half2-paired, SOFTWARE-PIPELINED:
// one masked 32-edge batch per node (16 pair-slots; invalid lanes clamp idx
// to the self-loop node and force w=0 -- absorbs the odd tail), with the NEXT
// node's idx batch issued before waiting on the current node's asrc/rows.
// Steady state: 1 row-latency per node instead of idx+row+tail serial chain.
// deg>32 handled by a rare serial fallback (P ~ 2e-4).
__global__ void k_agg2p(const __half* __restrict__ xh2, const float* __restrict__ asrc,
                        const float* __restrict__ adst, const int* __restrict__ offs,
                        const int* __restrict__ ssrc, const float* __restrict__ b2,
                        const int* __restrict__ batch, int N,
                        float* sums, int* counts){
    int tid = threadIdx.x;
    int lane = tid & 63, wv = tid >> 6;  // 4 waves/block
    int c = lane & 31;     // channel pair: channels 2c, 2c+1
    int half = lane >> 5;  // 0 or 1
    int wid = blockIdx.x * 4 + wv;
    int nw = gridDim.x * 4;
    int chunk = (N + nw - 1) / nw;
    int beg = wid * chunk, end = min(beg + chunk, N);
    if (beg >= end) return;
    const unsigned int* xrow = (const unsigned int*)xh2;   // 32 dwords per row
    float b2a = b2[2 * c], b2b = b2[2 * c + 1];
    float pacc0 = 0.f, pacc1 = 0.f; int pcnt = 0; int cur = batch[beg];

    int e0 = offs[beg], e1 = offs[beg + 1];
    int idxv[16];
#pragma unroll
    for (int u = 0; u < 16; u++){
        int j = e0 + 2 * u + half;
        idxv[u] = (j < e1) ? ssrc[j] : beg;   // clamp to self-loop node
    }
    for (int n = beg; n < end; n++){
        int e2 = (n + 1 < end) ? offs[n + 2] : e1;
        float ad = adst[n];
        // issue asrc + row gathers for node n (idxv prefetched last iter)
        float av[16];
        unsigned int rv[16];
#pragma unroll
        for (int u = 0; u < 16; u++){
            av[u] = asrc[idxv[u]];
            rv[u] = xrow[(size_t)idxv[u] * 32 + c];
        }
        // prefetch next node's idx batch (independent of av/rv results)
        int nidxv[16];
#pragma unroll
        for (int u = 0; u < 16; u++) nidxv[u] = 0;
        if (n + 1 < end){
#pragma unroll
            for (int u = 0; u < 16; u++){
                int j = e1 + 2 * u + half;
                nidxv[u] = (j < e2) ? ssrc[j] : (n + 1);
            }
        }
        // compute node n
        float acc0 = 0.f, acc1 = 0.f, den = 0.f;
#pragma unroll
        for (int u = 0; u < 16; u++){
            bool v = (e0 + 2 * u + half) < e1;
            float w = v ? __expf(lrelu(av[u] + ad)) : 0.f;
            float2 f = __half22float2(*(const __half2*)&rv[u]);
            acc0 += w * f.x;
            acc1 += w * f.y;
            den  += w;
        }
        // rare overflow: deg > 32
        if (e1 - e0 > 32){
            int j = e0 + 32;
            for (; j + 2 <= e1; j += 2){
                int s = ssrc[j + half];
                float a = asrc[s];
                unsigned int rr = xrow[(size_t)s * 32 + c];
                float w = __expf(lrelu(a + ad));
                float2 f = __half22float2(*(const __half2*)&rr);
                acc0 += w * f.x; acc1 += w * f.y; den += w;
            }
            if (j < e1){
                int s = ssrc[j];
                float w = (half == 0) ? __expf(lrelu(asrc[s] + ad)) : 0.f;
                unsigned int rr = xrow[(size_t)s * 32 + c];
                float2 f = __half22float2(*(const __half2*)&rr);
                acc0 += w * f.x; acc1 += w * f.y; den += w;
            }
        }
        acc0 += __shfl_xor(acc0, 32, 64);
        acc1 += __shfl_xor(acc1, 32, 64);
        den  += __shfl_xor(den, 32, 64);
        float h2a = elu_(acc0 / den + b2a);
        float h2b = elu_(acc1 / den + b2b);
        int g = batch[n];
        if (g != cur){
            if (half == 0){
                atomicAdd(&sums[cur * HID + 2 * c    ], pacc0);
                atomicAdd(&sums[cur * HID + 2 * c + 1], pacc1);
            }
            if (lane == 0) atomicAdd(&counts[cur], pcnt);
            pacc0 = 0.f; pacc1 = 0.f; pcnt = 0; cur = g;
        }
        pacc0 += h2a; pacc1 += h2b; pcnt++;
        // rotate pipeline state
        e0 = e1; e1 = e2;
#pragma unroll
        for (int u = 0; u < 16; u++) idxv[u] = nidxv[u];
    }
    if (half == 0){
        atomicAdd(&sums[cur * HID + 2 * c    ], pacc0);
        atomicAdd(&sums[cur * HID + 2 * c + 1], pacc1);
    }
    if (lane == 0) atomicAdd(&counts[cur], pcnt);
}

__global__ void k_final(const float* __restrict__ sums, const int* __restrict__ counts,
                        const float* __restrict__ Wl, const float* __restrict__ bl,
                        float* out){
    int t = threadIdx.x;
    if (t >= GR * 2) return;
    int g = t >> 1, task = t & 1;
    float c = (float)max(counts[g], 1);
    float acc = 0.f;
#pragma unroll
    for (int k = 0; k < HID; k++)
        acc += (sums[g * HID + k] / c) * Wl[k * 2 + task];
    out[t] = acc + bl[task];
}

extern "C" void kernel_launch(void* const* d_in, const int* in_sizes, int n_in,
                              void* d_out, int out_size, void* d_ws, size_t ws_size,
                              hipStream_t stream) {
    const float* x    = (const float*)d_in[0];
    const int*   ei   = (const int*)  d_in[1];
    const int*   batch= (const int*)  d_in[2];
    const float* W1   = (const float*)d_in[3];
    const float* as1  = (const float*)d_in[4];
    const float* ad1  = (const float*)d_in[5];
    const float* b1   = (const float*)d_in[6];
    const float* W2   = (const float*)d_in[7];
    const float* as2  = (const float*)d_in[8];
    const float* ad2  = (const float*)d_in[9];
    const float* b2   = (const float*)d_in[10];
    const float* Wl   = (const float*)d_in[11];
    const float* bl   = (const float*)d_in[12];
    float* out = (float*)d_out;

    int N  = in_sizes[0] / 2;
    int E  = in_sizes[1] / 2;
    int Et = E + N;
    const int* srcp = ei;
    const int* dstp = ei + E;

    char* p = (char*)d_ws;
    auto alloc = [&](size_t bytes)->char* {
        char* r = p; p += (bytes + 255) & ~(size_t)255; return r;
    };
    int*    offs   = (int*)   alloc((size_t)(N + 1) * 4);
    int*    bcnt   = (int*)   alloc(NBKT_MAX * 4);
    int*    bbase  = (int*)   alloc((NBKT_MAX + 1) * 4);
    int*    bcursor= (int*)   alloc(NBKT_MAX * 4);
    int*    ssrc   = (int*)   alloc((size_t)Et * 4);
    unsigned int* tmp = (unsigned int*)alloc((size_t)E * 4);
    float*  cvec   = (float*) alloc(16 * 4);
    float4* Sa     = (float4*)alloc((size_t)N * 16);
    float4* Sb     = (float4*)alloc((size_t)N * 16);
    float4* Sc     = (float4*)alloc((size_t)N * 16);
    float*  asrc2  = (float*) alloc((size_t)N * 4);
    float*  adst2  = (float*) alloc((size_t)N * 4);
    float*  sums   = (float*) alloc((size_t)GR * HID * 4);
    int*    counts = (int*)   alloc((size_t)GR * 4);
    uint4*  w2frag = (uint4*) alloc(2048 * 16);
    __half* xh2    = (__half*)alloc((size_t)N * 64 * 2);

    int nbkt = (N + 255) >> BK_SH;

    k_init <<<16, 256, 0, stream>>>(sums, counts, bcnt, W1, as1, ad1, cvec);
    k_histW<<<264, 256, 0, stream>>>(dstp, E, bcnt, W2, w2frag);
    k_bscan<<<1, NBKT_MAX, 0, stream>>>(bcnt, bbase, bcursor);
    k_part <<<(E + PART_T - 1) / PART_T, 256, 0, stream>>>(srcp, dstp, E, bcursor, tmp);
    k_csr2 <<<nbkt, 256, 0, stream>>>(tmp, bbase, N, Et, offs, ssrc);

    k_agg1s<<<((N * 4) + 255) / 256, 256, 0, stream>>>(x, offs, ssrc, cvec, N, Sa, Sb, Sc);
    k_mfma <<<1024, 256, 0, stream>>>(Sa, Sb, Sc, W1, b1, w2frag, as2, ad2,
                                      N, xh2, asrc2, adst2);
    k_agg2p<<<2048, 256, 0, stream>>>(xh2, asrc2, adst2, offs, ssrc, b2,
                                      batch, N, sums, counts);
    k_final<<<1, 128, 0, stream>>>(sums, counts, Wl, bl, out);
}

// Round 14
// 188.798 us; speedup vs baseline: 1.1442x; 1.1268x over previous
//
#include <hip/hip_runtime.h>
#include <hip/hip_fp16.h>
#include <math.h>

#define HID 64
#define HEADS 4
#define GR 64
#define NEG 0.2f
#define NBKT_MAX 512
#define BK_SH 8     // 256 nodes per bucket
#define PART_T 4096 // edges per partition tile
// tmp edge pack: (dst & 255) << 17 | src   -- requires N < 2^17 (N=100000 ok)

typedef _Float16 f16x8 __attribute__((ext_vector_type(8)));
typedef float    f32x4 __attribute__((ext_vector_type(4)));

__device__ __forceinline__ float lrelu(float v){ return v > 0.f ? v : NEG * v; }
__device__ __forceinline__ float elu_(float v){ return v > 0.f ? v : __expf(v) - 1.f; }

// zero pooled sums/counts/bucket-counts; block 0 wave 0 also computes the
// attention-projection constants cvec = [cs0(4), cs1(4), cd0(4), cd1(4)].
// (must run EVERY call: harness does not re-poison ws between timed replays)
__global__ void k_init(float* sums, int* counts, int* bcnt,
                       const float* __restrict__ W1, const float* __restrict__ as1,
                       const float* __restrict__ ad1, float* cvec){
    int i = blockIdx.x * blockDim.x + threadIdx.x;
    if (i < GR * HID) sums[i] = 0.f;
    if (i < GR) counts[i] = 0;
    if (i < NBKT_MAX) bcnt[i] = 0;
    if (blockIdx.x == 0 && threadIdx.x < 64){
        int lane = threadIdx.x;
#pragma unroll
        for (int h = 0; h < HEADS; h++){
            int j = h * HID + lane;
            float s0 = W1[j]       * as1[j];
            float s1 = W1[256 + j] * as1[j];
            float d0 = W1[j]       * ad1[j];
            float d1 = W1[256 + j] * ad1[j];
#pragma unroll
            for (int off = 32; off; off >>= 1){
                s0 += __shfl_xor(s0, off, 64);
                s1 += __shfl_xor(s1, off, 64);
                d0 += __shfl_xor(d0, off, 64);
                d1 += __shfl_xor(d1, off, 64);
            }
            if (lane == 0){
                cvec[h] = s0; cvec[4 + h] = s1; cvec[8 + h] = d0; cvec[12 + h] = d1;
            }
        }
    }
}

// merged: blocks 0..255 bucket histogram; blocks 256..263 pack W2 fragments.
__global__ void k_histW(const int* __restrict__ dst, int E, int* bcnt,
                        const float* __restrict__ W2, uint4* __restrict__ w2frag){
    __shared__ int bh[NBKT_MAX];
    if (blockIdx.x < 256){
        for (int b = threadIdx.x; b < NBKT_MAX; b += blockDim.x) bh[b] = 0;
        __syncthreads();
        int stride = 256 * blockDim.x;
        for (int i = blockIdx.x * blockDim.x + threadIdx.x; i < E; i += stride)
            atomicAdd(&bh[dst[i] >> BK_SH], 1);
        __syncthreads();
        for (int b = threadIdx.x; b < NBKT_MAX; b += blockDim.x)
            if (bh[b]) atomicAdd(&bcnt[b], bh[b]);
    } else {
        int t = (blockIdx.x - 256) * 256 + threadIdx.x;
        if (t < 2048){
            int lane = t & 63, c = (t >> 6) & 3, s = t >> 8;
            union { uint4 u; _Float16 h[8]; } o;
#pragma unroll
            for (int e = 0; e < 8; e++){
                int k = 32 * s + 4 * (lane >> 4) + (e & 3) + 16 * (e >> 2);
                int col = 16 * c + (lane & 15);
                o.h[e] = (_Float16)W2[k * 64 + col];
            }
            w2frag[t] = o.u;
        }
    }
}

// exclusive scan of bucket counts -> bucket bases + partition cursors.
__global__ void k_bscan(const int* __restrict__ bcnt, int* bbase, int* bcursor){
    __shared__ int sh[NBKT_MAX];
    int t = threadIdx.x;     // 512 threads
    int v = bcnt[t];
    sh[t] = v;
    __syncthreads();
    for (int off = 1; off < NBKT_MAX; off <<= 1){
        int u = (t >= off) ? sh[t - off] : 0;
        __syncthreads();
        sh[t] += u;
        __syncthreads();
    }
    bbase[t] = sh[t] - v;
    bcursor[t] = sh[t] - v;
    if (t == NBKT_MAX - 1) bbase[NBKT_MAX] = sh[t];
}

// staged partition: per-tile LDS bucket count -> one global reserve per
// (block,bucket) -> scatter packed u32 (dloc<<17|src) into block-private runs.
__global__ void __launch_bounds__(256)
k_part(const int* __restrict__ src, const int* __restrict__ dst, int E,
       int* bcursor, unsigned int* __restrict__ tmp){
    __shared__ int bh[NBKT_MAX];
    __shared__ int gbl[NBKT_MAX];
    int tid = threadIdx.x;
    int base = blockIdx.x * PART_T;
    for (int b = tid; b < NBKT_MAX; b += 256) bh[b] = 0;
    __syncthreads();
#pragma unroll
    for (int r = 0; r < PART_T / 256; r++){
        int i = base + r * 256 + tid;
        if (i < E) atomicAdd(&bh[dst[i] >> BK_SH], 1);
    }
    __syncthreads();
    for (int b = tid; b < NBKT_MAX; b += 256){
        int c = bh[b];
        gbl[b] = c ? atomicAdd(&bcursor[b], c) : 0;
        bh[b] = 0;
    }
    __syncthreads();
#pragma unroll
    for (int r = 0; r < PART_T / 256; r++){
        int i = base + r * 256 + tid;
        if (i < E){
            int s = src[i], d = dst[i];
            int b = d >> BK_SH;
            int rank = atomicAdd(&bh[b], 1);
            tmp[(size_t)(gbl[b] + rank)] =
                ((unsigned)(d & ((1 << BK_SH) - 1)) << 17) | (unsigned)s;
        }
    }
}

// per-bucket CSR emit, deriving per-node offs locally:
// offs[n] = bbase[b] + n0 + excl_scan_local(deg_local+1)
__global__ void __launch_bounds__(256)
k_csr2(const unsigned int* __restrict__ tmp, const int* __restrict__ bbase,
       int N, int Et, int* __restrict__ offs, int* __restrict__ ssrc){
    __shared__ int degl[256];
    __shared__ int rc[256];
    __shared__ int scan[256];
    __shared__ int ofl[256];
    int b = blockIdx.x, tid = threadIdx.x;
    int n0 = b << BK_SH;
    int nloc = min(256, N - n0);
    degl[tid] = 0; rc[tid] = 0;
    __syncthreads();
    int beg = bbase[b], cnt = bbase[b + 1] - beg;
    for (int i = tid; i < cnt; i += 256)
        atomicAdd(&degl[tmp[beg + i] >> 17], 1);
    __syncthreads();
    int v = (tid < nloc) ? degl[tid] + 1 : 0;
    scan[tid] = v;
    __syncthreads();
    for (int off = 1; off < 256; off <<= 1){
        int u = (tid >= off) ? scan[tid - off] : 0;
        __syncthreads();
        scan[tid] += u;
        __syncthreads();
    }
    int base = beg + n0;
    if (tid < nloc){
        int o = base + scan[tid] - v;   // exclusive
        ofl[tid] = o;
        offs[n0 + tid] = o;
        ssrc[o] = n0 + tid;             // self-loop first
    }
    if (b == 0 && tid == 0) offs[N] = Et;
    __syncthreads();
    for (int i = tid; i < cnt; i += 256){
        unsigned int e = tmp[beg + i];
        int dloc = (int)(e >> 17);
        int s = (int)(e & 0x1FFFFu);
        int pos = ofl[dloc] + 1 + atomicAdd(&rc[dloc], 1);
        ssrc[pos] = s;
    }
}

// layer-1 aggregation via rank-2 trick, 4 lanes per node (stride-4 edge split,
// 2-step shfl_xor reduce of the 12 scalars). 400k threads = 24 waves/CU.
__global__ void k_agg1s(const float* __restrict__ x, const int* __restrict__ offs,
                        const int* __restrict__ ssrc, const float* __restrict__ cvec,
                        int N, float4* Sa, float4* Sb, float4* Sc){
    int t = blockIdx.x * blockDim.x + threadIdx.x;
    int n = t >> 2, sub = t & 3;
    if (n >= N) return;
    float4 cs0 = ((const float4*)cvec)[0];
    float4 cs1 = ((const float4*)cvec)[1];
    float4 cd0 = ((const float4*)cvec)[2];
    float4 cd1 = ((const float4*)cvec)[3];
    float c0[4] = {cs0.x, cs0.y, cs0.z, cs0.w};
    float c1[4] = {cs1.x, cs1.y, cs1.z, cs1.w};
    float2 xn = ((const float2*)x)[n];
    float ad[4] = {xn.x*cd0.x + xn.y*cd1.x, xn.x*cd0.y + xn.y*cd1.y,
                   xn.x*cd0.z + xn.y*cd1.z, xn.x*cd0.w + xn.y*cd1.w};
    float A0[4] = {0,0,0,0}, A1[4] = {0,0,0,0}, D[4] = {0,0,0,0};
    int beg = offs[n], end = offs[n + 1];
    int j = beg + sub;
    for (; j + 12 < end; j += 16){     // 4 edges/lane/iter (stride 4)
        int si[4] = {ssrc[j], ssrc[j+4], ssrc[j+8], ssrc[j+12]};
        float2 xs[4];
#pragma unroll
        for (int u = 0; u < 4; u++) xs[u] = ((const float2*)x)[si[u]];
#pragma unroll
        for (int h = 0; h < HEADS; h++){
#pragma unroll
            for (int u = 0; u < 4; u++){
                float w = __expf(lrelu(xs[u].x * c0[h] + xs[u].y * c1[h] + ad[h]));
                A0[h] += w * xs[u].x;
                A1[h] += w * xs[u].y;
                D[h]  += w;
            }
        }
    }
    for (; j < end; j += 4){
        int s = ssrc[j];
        float2 xs = ((const float2*)x)[s];
#pragma unroll
        for (int h = 0; h < HEADS; h++){
            float e = xs.x * c0[h] + xs.y * c1[h] + ad[h];
            float w = __expf(lrelu(e));
            A0[h] += w * xs.x;
            A1[h] += w * xs.y;
            D[h]  += w;
        }
    }
#pragma unroll
    for (int h = 0; h < HEADS; h++){
        A0[h] += __shfl_xor(A0[h], 1, 64); A0[h] += __shfl_xor(A0[h], 2, 64);
        A1[h] += __shfl_xor(A1[h], 1, 64); A1[h] += __shfl_xor(A1[h], 2, 64);
        D[h]  += __shfl_xor(D[h],  1, 64); D[h]  += __shfl_xor(D[h],  2, 64);
    }
    if (sub == 0){
        Sa[n] = make_float4(A0[0], A0[1], A0[2], A0[3]);
        Sb[n] = make_float4(A1[0], A1[1], A1[2], A1[3]);
        Sc[n] = make_float4(D[0],  D[1],  D[2],  D[3]);
    }
}

// Fused MFMA layer-2 GEMM: A-fragments (h1 rows) computed in-register from
// the 12 per-node scalars; W1/b1 + W2 fragments staged in LDS.
__global__ void __launch_bounds__(256)
k_mfma(const float4* __restrict__ Sa4, const float4* __restrict__ Sb4,
       const float4* __restrict__ Sc4, const float* __restrict__ W1,
       const float* __restrict__ b1, const uint4* __restrict__ w2frag,
       const float* __restrict__ as2, const float* __restrict__ ad2,
       int N, __half* __restrict__ xh2, float* __restrict__ asrc,
       float* __restrict__ adst){
    __shared__ uint4 w2s[2048];                      // 32 KB B fragments
    __shared__ float4 w1aS[64], w1bS[64], b1S[64];   // 3 KB W1 rows + b1
    int tid = threadIdx.x;
    for (int i = tid; i < 2048; i += 256) w2s[i] = w2frag[i];
    if (tid < 64){
        w1aS[tid] = ((const float4*)W1)[tid];
        w1bS[tid] = ((const float4*)W1)[tid + 64];
        b1S[tid]  = ((const float4*)b1)[tid];
    }
    __syncthreads();

    int lane = tid & 63, wv = tid >> 6;
    int r = lane & 15, g = lane >> 4;
    float asw0 = as2[r], asw1 = as2[16 + r], asw2 = as2[32 + r], asw3 = as2[48 + r];
    float adw0 = ad2[r], adw1 = ad2[16 + r], adw2 = ad2[32 + r], adw3 = ad2[48 + r];

    int ntiles = (N + 15) >> 4;
    for (int t = blockIdx.x * 4 + wv; t < ntiles; t += gridDim.x * 4){
        int base = t << 4;
        int nodeA = min(base + r, N - 1);
        float4 sa = Sa4[nodeA], sb = Sb4[nodeA], sc = Sc4[nodeA];
        float rdv0 = 1.0f / sc.x, rdv1 = 1.0f / sc.y;
        float rdv2 = 1.0f / sc.z, rdv3 = 1.0f / sc.w;
        f32x4 ac0 = {0.f,0.f,0.f,0.f}, ac1 = {0.f,0.f,0.f,0.f};
        f32x4 ac2 = {0.f,0.f,0.f,0.f}, ac3 = {0.f,0.f,0.f,0.f};
#pragma unroll
        for (int s = 0; s < 8; s++){
            const int head = s >> 1;                 // compile-time
            float A0 = head == 0 ? sa.x : head == 1 ? sa.y : head == 2 ? sa.z : sa.w;
            float A1 = head == 0 ? sb.x : head == 1 ? sb.y : head == 2 ? sb.z : sb.w;
            float rd = head == 0 ? rdv0 : head == 1 ? rdv1 : head == 2 ? rdv2 : rdv3;
            int q0 = 8 * s + g;
            float4 w0lo = w1aS[q0], w0hi = w1aS[q0 + 4];
            float4 w1lo = w1bS[q0], w1hi = w1bS[q0 + 4];
            float4 blo  = b1S[q0],  bhi  = b1S[q0 + 4];
            union { uint4 u; f16x8 f; _Float16 h[8]; } a;
            a.h[0] = (_Float16)elu_((A0 * w0lo.x + A1 * w1lo.x) * rd + blo.x);
            a.h[1] = (_Float16)elu_((A0 * w0lo.y + A1 * w1lo.y) * rd + blo.y);
            a.h[2] = (_Float16)elu_((A0 * w0lo.z + A1 * w1lo.z) * rd + blo.z);
            a.h[3] = (_Float16)elu_((A0 * w0lo.w + A1 * w1lo.w) * rd + blo.w);
            a.h[4] = (_Float16)elu_((A0 * w0hi.x + A1 * w1hi.x) * rd + bhi.x);
            a.h[5] = (_Float16)elu_((A0 * w0hi.y + A1 * w1hi.y) * rd + bhi.y);
            a.h[6] = (_Float16)elu_((A0 * w0hi.z + A1 * w1hi.z) * rd + bhi.z);
            a.h[7] = (_Float16)elu_((A0 * w0hi.w + A1 * w1hi.w) * rd + bhi.w);
            union { uint4 u; f16x8 f; } b0, b1x, b2, b3;
            b0.u  = w2s[(s * 4 + 0) * 64 + lane];
            b1x.u = w2s[(s * 4 + 1) * 64 + lane];
            b2.u  = w2s[(s * 4 + 2) * 64 + lane];
            b3.u  = w2s[(s * 4 + 3) * 64 + lane];
            ac0 = __builtin_amdgcn_mfma_f32_16x16x32_f16(a.f, b0.f,  ac0, 0, 0, 0);
            ac1 = __builtin_amdgcn_mfma_f32_16x16x32_f16(a.f, b1x.f, ac1, 0, 0, 0);
            ac2 = __builtin_amdgcn_mfma_f32_16x16x32_f16(a.f, b2.f,  ac2, 0, 0, 0);
            ac3 = __builtin_amdgcn_mfma_f32_16x16x32_f16(a.f, b3.f,  ac3, 0, 0, 0);
        }
        float ps0 = 0.f, ps1 = 0.f, ps2 = 0.f, ps3 = 0.f;
        float pd0 = 0.f, pd1 = 0.f, pd2 = 0.f, pd3 = 0.f;
#pragma unroll
        for (int reg = 0; reg < 4; reg++){
            int node = base + 4 * g + reg;
            if (node < N){
                size_t rowb = (size_t)node * 64;
                xh2[rowb +      r] = __float2half(ac0[reg]);
                xh2[rowb + 16 + r] = __float2half(ac1[reg]);
                xh2[rowb + 32 + r] = __float2half(ac2[reg]);
                xh2[rowb + 48 + r] = __float2half(ac3[reg]);
            }
            float ps = ac0[reg]*asw0 + ac1[reg]*asw1 + ac2[reg]*asw2 + ac3[reg]*asw3;
            float pd = ac0[reg]*adw0 + ac1[reg]*adw1 + ac2[reg]*adw2 + ac3[reg]*adw3;
            if (reg == 0){ ps0 = ps; pd0 = pd; }
            else if (reg == 1){ ps1 = ps; pd1 = pd; }
            else if (reg == 2){ ps2 = ps; pd2 = pd; }
            else { ps3 = ps; pd3 = pd; }
        }
#pragma unroll
        for (int m = 1; m < 16; m <<= 1){
            ps0 += __shfl_xor(ps0, m, 64); pd0 += __shfl_xor(pd0, m, 64);
            ps1 += __shfl_xor(ps1, m, 64); pd1 += __shfl_xor(pd1, m, 64);
            ps2 += __shfl_xor(ps2, m, 64); pd2 += __shfl_xor(pd2, m, 64);
            ps3 += __shfl_xor(ps3, m, 64); pd3 += __shfl_xor(pd3, m, 64);
        }
        if (r == 0){
            int nb = base + 4 * g;
            if (nb     < N){ asrc[nb    ] = ps0; adst[nb    ] = pd0; }
            if (nb + 1 < N){ asrc[nb + 1] = ps1; adst[nb + 1] = pd1; }
            if (nb + 2 < N){ asrc[nb + 2] = ps2; adst[nb + 2] = pd2; }
            if (nb + 3 < N){ asrc[nb + 3] = ps3; adst[nb + 3] = pd3; }
        }
    }
}

// layer-2 aggregation fused with mean pool, half2-paired, unrolled to
// 16 edges (8 pairs). R11-proven configuration (86 us): the latency-bound
// optimum for this random-gather structure (R12 coop-gather and R13 masked
// pipeline both regressed it).
__global__ void k_agg2p(const __half* __restrict__ xh2, const float* __restrict__ asrc,
                        const float* __restrict__ adst, const int* __restrict__ offs,
                        const int* __restrict__ ssrc, const float* __restrict__ b2,
                        const int* __restrict__ batch, int N,
                        float* sums, int* counts){
    int tid = threadIdx.x;
    int lane = tid & 63, wv = tid >> 6;  // 4 waves/block
    int c = lane & 31;     // channel pair: channels 2c, 2c+1
    int half = lane >> 5;  // 0 or 1
    int wid = blockIdx.x * 4 + wv;
    int nw = gridDim.x * 4;
    int chunk = (N + nw - 1) / nw;
    int beg = wid * chunk, end = min(beg + chunk, N);
    if (beg >= end) return;
    const unsigned int* xrow = (const unsigned int*)xh2;   // 32 dwords per row
    float b2a = b2[2 * c], b2b = b2[2 * c + 1];
    float pacc0 = 0.f, pacc1 = 0.f; int pcnt = 0; int cur = batch[beg];
    for (int n = beg; n < end; n++){
        float ad = adst[n];
        float acc0 = 0.f, acc1 = 0.f, den = 0.f;
        int e0 = offs[n], e1 = offs[n + 1];
        int j = e0;
        for (; j + 16 <= e1; j += 16){  // 8 pairs = 16 edges
            int si[8];
#pragma unroll
            for (int u = 0; u < 8; u++) si[u] = ssrc[j + 2 * u + half];
            float av[8];
#pragma unroll
            for (int u = 0; u < 8; u++) av[u] = asrc[si[u]];
            unsigned int rv[8];
#pragma unroll
            for (int u = 0; u < 8; u++) rv[u] = xrow[(size_t)si[u] * 32 + c];
#pragma unroll
            for (int u = 0; u < 8; u++){
                float w = __expf(lrelu(av[u] + ad));
                float2 f = __half22float2(*(const __half2*)&rv[u]);
                acc0 += w * f.x;
                acc1 += w * f.y;
                den  += w;
            }
        }
        if (j + 8 <= e1){              // 4 pairs
            int si[4];
#pragma unroll
            for (int u = 0; u < 4; u++) si[u] = ssrc[j + 2 * u + half];
            float av[4];
#pragma unroll
            for (int u = 0; u < 4; u++) av[u] = asrc[si[u]];
            unsigned int rv[4];
#pragma unroll
            for (int u = 0; u < 4; u++) rv[u] = xrow[(size_t)si[u] * 32 + c];
#pragma unroll
            for (int u = 0; u < 4; u++){
                float w = __expf(lrelu(av[u] + ad));
                float2 f = __half22float2(*(const __half2*)&rv[u]);
                acc0 += w * f.x;
                acc1 += w * f.y;
                den  += w;
            }
            j += 8;
        }
        for (; j + 2 <= e1; j += 2){   // single pair
            int s = ssrc[j + half];
            float a = asrc[s];
            unsigned int rr = xrow[(size_t)s * 32 + c];
            float w = __expf(lrelu(a + ad));
            float2 f = __half22float2(*(const __half2*)&rr);
            acc0 += w * f.x;
            acc1 += w * f.y;
            den  += w;
        }
        if (j < e1){                   // odd tail: half 1 contributes zero
            int s = ssrc[j];
            float w = (half == 0) ? __expf(lrelu(asrc[s] + ad)) : 0.f;
            unsigned int rr = xrow[(size_t)s * 32 + c];
            float2 f = __half22float2(*(const __half2*)&rr);
            acc0 += w * f.x;
            acc1 += w * f.y;
            den  += w;
        }
        acc0 += __shfl_xor(acc0, 32, 64);
        acc1 += __shfl_xor(acc1, 32, 64);
        den  += __shfl_xor(den, 32, 64);
        float h2a = elu_(acc0 / den + b2a);
        float h2b = elu_(acc1 / den + b2b);
        int g = batch[n];
        if (g != cur){
            if (half == 0){
                atomicAdd(&sums[cur * HID + 2 * c    ], pacc0);
                atomicAdd(&sums[cur * HID + 2 * c + 1], pacc1);
            }
            if (lane == 0) atomicAdd(&counts[cur], pcnt);
            pacc0 = 0.f; pacc1 = 0.f; pcnt = 0; cur = g;
        }
        pacc0 += h2a; pacc1 += h2b; pcnt++;
    }
    if (half == 0){
        atomicAdd(&sums[cur * HID + 2 * c    ], pacc0);
        atomicAdd(&sums[cur * HID + 2 * c + 1], pacc1);
    }
    if (lane == 0) atomicAdd(&counts[cur], pcnt);
}

__global__ void k_final(const float* __restrict__ sums, const int* __restrict__ counts,
                        const float* __restrict__ Wl, const float* __restrict__ bl,
                        float* out){
    int t = threadIdx.x;
    if (t >= GR * 2) return;
    int g = t >> 1, task = t & 1;
    float c = (float)max(counts[g], 1);
    float acc = 0.f;
#pragma unroll
    for (int k = 0; k < HID; k++)
        acc += (sums[g * HID + k] / c) * Wl[k * 2 + task];
    out[t] = acc + bl[task];
}

extern "C" void kernel_launch(void* const* d_in, const int* in_sizes, int n_in,
                              void* d_out, int out_size, void* d_ws, size_t ws_size,
                              hipStream_t stream) {
    const float* x    = (const float*)d_in[0];
    const int*   ei   = (const int*)  d_in[1];
    const int*   batch= (const int*)  d_in[2];
    const float* W1   = (const float*)d_in[3];
    const float* as1  = (const float*)d_in[4];
    const float* ad1  = (const float*)d_in[5];
    const float* b1   = (const float*)d_in[6];
    const float* W2   = (const float*)d_in[7];
    const float* as2  = (const float*)d_in[8];
    const float* ad2  = (const float*)d_in[9];
    const float* b2   = (const float*)d_in[10];
    const float* Wl   = (const float*)d_in[11];
    const float* bl   = (const float*)d_in[12];
    float* out = (float*)d_out;

    int N  = in_sizes[0] / 2;
    int E  = in_sizes[1] / 2;
    int Et = E + N;
    const int* srcp = ei;
    const int* dstp = ei + E;

    char* p = (char*)d_ws;
    auto alloc = [&](size_t bytes)->char* {
        char* r = p; p += (bytes + 255) & ~(size_t)255; return r;
    };
    int*    offs   = (int*)   alloc((size_t)(N + 1) * 4);
    int*    bcnt   = (int*)   alloc(NBKT_MAX * 4);
    int*    bbase  = (int*)   alloc((NBKT_MAX + 1) * 4);
    int*    bcursor= (int*)   alloc(NBKT_MAX * 4);
    int*    ssrc   = (int*)   alloc((size_t)Et * 4);
    unsigned int* tmp = (unsigned int*)alloc((size_t)E * 4);
    float*  cvec   = (float*) alloc(16 * 4);
    float4* Sa     = (float4*)alloc((size_t)N * 16);
    float4* Sb     = (float4*)alloc((size_t)N * 16);
    float4* Sc     = (float4*)alloc((size_t)N * 16);
    float*  asrc2  = (float*) alloc((size_t)N * 4);
    float*  adst2  = (float*) alloc((size_t)N * 4);
    float*  sums   = (float*) alloc((size_t)GR * HID * 4);
    int*    counts = (int*)   alloc((size_t)GR * 4);
    uint4*  w2frag = (uint4*) alloc(2048 * 16);
    __half* xh2    = (__half*)alloc((size_t)N * 64 * 2);

    int nbkt = (N + 255) >> BK_SH;

    k_init <<<16, 256, 0, stream>>>(sums, counts, bcnt, W1, as1, ad1, cvec);
    k_histW<<<264, 256, 0, stream>>>(dstp, E, bcnt, W2, w2frag);
    k_bscan<<<1, NBKT_MAX, 0, stream>>>(bcnt, bbase, bcursor);
    k_part <<<(E + PART_T - 1) / PART_T, 256, 0, stream>>>(srcp, dstp, E, bcursor, tmp);
    k_csr2 <<<nbkt, 256, 0, stream>>>(tmp, bbase, N, Et, offs, ssrc);

    k_agg1s<<<((N * 4) + 255) / 256, 256, 0, stream>>>(x, offs, ssrc, cvec, N, Sa, Sb, Sc);
    k_mfma <<<1024, 256, 0, stream>>>(Sa, Sb, Sc, W1, b1, w2frag, as2, ad2,
                                      N, xh2, asrc2, adst2);
    k_agg2p<<<2048, 256, 0, stream>>>(xh2, asrc2, adst2, offs, ssrc, b2,
                                      batch, N, sums, counts);
    k_final<<<1, 128, 0, stream>>>(sums, counts, Wl, bl, out);
}